// Round 12
// baseline (59.602 us; speedup 1.0000x reference)
//
#include <hip/hip_runtime.h>
#include <hip/hip_bf16.h>
#include <math.h>

#define CIN 256
#define COUT 768   // 3 * OUTC
#define OUTC 256
#define HH 64
#define WW 64
#define HW 4096

typedef unsigned int uint32;
typedef unsigned short ushort16;
typedef unsigned long long u64;

using short8 = __attribute__((ext_vector_type(8))) short;
using f32x4  = __attribute__((ext_vector_type(4))) float;
using hf2    = __attribute__((ext_vector_type(2))) _Float16;

__device__ inline uint32 pkbf2(float a, float b) {
    __hip_bfloat162 h = __float22bfloat162_rn(make_float2(a, b));
    union { __hip_bfloat162 h2; uint32 u; } cv; cv.h2 = h;
    return cv.u;
}
__device__ inline uint32 pkhf2(float a, float b) {
    union { _Float16 h[2]; uint32 u; } cv;
    cv.h[0] = (_Float16)a; cv.h[1] = (_Float16)b;
    return cv.u;
}
__device__ inline float dpp_xor1(float x) {
#if __has_builtin(__builtin_amdgcn_update_dpp)
    int i = __builtin_amdgcn_update_dpp(0, __float_as_int(x),
                                        0xB1, 0xF, 0xF, true);   // quad_perm [1,0,3,2]
    return __int_as_float(i);
#else
    return __shfl_xor(x, 1, 64);
#endif
}
__device__ inline float dpp_xor2(float x) {
#if __has_builtin(__builtin_amdgcn_update_dpp)
    int i = __builtin_amdgcn_update_dpp(0, __float_as_int(x),
                                        0x4E, 0xF, 0xF, true);   // quad_perm [2,3,0,1]
    return __int_as_float(i);
#else
    return __shfl_xor(x, 2, 64);
#endif
}
// f32 += dot(h2, h2) — v_dot2_f32_f16 if available, else unpack-fma
__device__ inline float dot2acc(hf2 a, hf2 b, float c) {
#if __has_builtin(__builtin_amdgcn_fdot2)
    return __builtin_amdgcn_fdot2(a, b, c, false);
#else
    c = fmaf((float)a[0], (float)b[0], c);
    return fmaf((float)a[1], (float)b[1], c);
#endif
}

// ---------------------------------------------------------------------------
// Kernel 1: QKV projection (EXACT R10/R11 body, ~22 us).
// Output: qkv_f16[n][slot=d>>5][p][dlow=d&31]
// ---------------------------------------------------------------------------
#define LDSTR 40   // shorts per LDS row (32 + 8 pad)

__global__ __launch_bounds__(256) void qkv_gemm_kernel(
    const float* __restrict__ x, const float* __restrict__ wq,
    const float* __restrict__ bq, ushort16* __restrict__ qkv)
{
    __shared__ __align__(16) char smem[32768];
    ushort16* As = (ushort16*)smem;            // [128][LDSTR]
    ushort16* Bs = (ushort16*)smem + 128 * LDSTR;

    const int n   = blockIdx.z;
    const int d0  = blockIdx.y * 128;
    const int p0  = blockIdx.x * 128;
    const int tid = threadIdx.x;
    const int lane = tid & 63;
    const int wid  = tid >> 6;
    const int wm = wid >> 1;
    const int wn = wid & 1;

    const float* xb = x + (size_t)n * CIN * HW;

    const int arow = tid >> 2;
    const int akk  = (tid & 3) * 8;
    const float* aptr = wq + (size_t)(d0 + arow) * CIN + akk;
    const int bkg = (tid >> 6) * 8;
    const int bpg = (tid & 63) * 2;
    const float* bptr = xb + (size_t)bkg * HW + p0 + bpg;

    ushort16* awr0 = &As[arow * LDSTR + akk];
    ushort16* awr1 = &As[(arow + 64) * LDSTR + akk];
    ushort16* bwr0 = &Bs[bpg * LDSTR + bkg];
    ushort16* bwr1 = &Bs[(bpg + 1) * LDSTR + bkg];

    f32x4 acc[4][4];
    #pragma unroll
    for (int i = 0; i < 4; ++i)
        #pragma unroll
        for (int j = 0; j < 4; ++j) acc[i][j] = (f32x4){0.f, 0.f, 0.f, 0.f};

    float4 a_st[4];
    float2 b_st[8];

    {
        a_st[0] = *(const float4*)(aptr);
        a_st[1] = *(const float4*)(aptr + 4);
        a_st[2] = *(const float4*)(aptr + (size_t)64 * CIN);
        a_st[3] = *(const float4*)(aptr + (size_t)64 * CIN + 4);
        #pragma unroll
        for (int j = 0; j < 8; ++j)
            b_st[j] = *(const float2*)(bptr + (size_t)j * HW);
    }

    const int lrow = lane & 15;
    const int lk   = (lane >> 4) * 8;

    #pragma unroll 1
    for (int kt = 0; kt < 8; ++kt) {
        __syncthreads();

        {
            uint32 w0 = pkbf2(a_st[0].x, a_st[0].y), w1 = pkbf2(a_st[0].z, a_st[0].w);
            uint32 w2 = pkbf2(a_st[1].x, a_st[1].y), w3 = pkbf2(a_st[1].z, a_st[1].w);
            *(uint4*)awr0 = make_uint4(w0, w1, w2, w3);
            w0 = pkbf2(a_st[2].x, a_st[2].y); w1 = pkbf2(a_st[2].z, a_st[2].w);
            w2 = pkbf2(a_st[3].x, a_st[3].y); w3 = pkbf2(a_st[3].z, a_st[3].w);
            *(uint4*)awr1 = make_uint4(w0, w1, w2, w3);
            uint4 c0, c1;
            c0.x = pkbf2(b_st[0].x, b_st[1].x); c0.y = pkbf2(b_st[2].x, b_st[3].x);
            c0.z = pkbf2(b_st[4].x, b_st[5].x); c0.w = pkbf2(b_st[6].x, b_st[7].x);
            c1.x = pkbf2(b_st[0].y, b_st[1].y); c1.y = pkbf2(b_st[2].y, b_st[3].y);
            c1.z = pkbf2(b_st[4].y, b_st[5].y); c1.w = pkbf2(b_st[6].y, b_st[7].y);
            *(uint4*)bwr0 = c0;
            *(uint4*)bwr1 = c1;
        }

        if (kt < 7) {
            const int ko = (kt + 1) * 32;
            a_st[0] = *(const float4*)(aptr + ko);
            a_st[1] = *(const float4*)(aptr + ko + 4);
            a_st[2] = *(const float4*)(aptr + (size_t)64 * CIN + ko);
            a_st[3] = *(const float4*)(aptr + (size_t)64 * CIN + ko + 4);
            #pragma unroll
            for (int j = 0; j < 8; ++j)
                b_st[j] = *(const float2*)(bptr + (size_t)(ko + j) * HW);
        }

        __syncthreads();

        short8 af[4], bf[4];
        #pragma unroll
        for (int fm = 0; fm < 4; ++fm)
            af[fm] = *(const short8*)&As[(wm * 64 + fm * 16 + lrow) * LDSTR + lk];
        #pragma unroll
        for (int fn = 0; fn < 4; ++fn)
            bf[fn] = *(const short8*)&Bs[(wn * 64 + fn * 16 + lrow) * LDSTR + lk];
        #pragma unroll
        for (int fm = 0; fm < 4; ++fm)
            #pragma unroll
            for (int fn = 0; fn < 4; ++fn)
                acc[fm][fn] = __builtin_amdgcn_mfma_f32_16x16x32_bf16(
                    af[fm], bf[fn], acc[fm][fn], 0, 0, 0);
    }

    // ---- epilogue: LDS transpose -> coalesced stores ----
    __syncthreads();

    u64* E = (u64*)smem + (size_t)wid * 1024;

    const int hi4 = lane >> 4;
    #pragma unroll
    for (int fm = 0; fm < 4; ++fm) {
        const int D = d0 + wm * 64 + fm * 16 + hi4 * 4;
        const float4 bias = *(const float4*)(&bq[D]);
        const int cell = fm * 2 + (hi4 >> 1);
        const int half = hi4 & 1;
        #pragma unroll
        for (int fn = 0; fn < 4; ++fn) {
            const int pl = fn * 16 + lrow;
            f32x4 v = acc[fm][fn];
            u64 pk = (u64)pkhf2(v[0] + bias.x, v[1] + bias.y)
                   | ((u64)pkhf2(v[2] + bias.z, v[3] + bias.w) << 32);
            E[pl * 16 + (cell ^ (pl & 7)) * 2 + half] = pk;
        }
    }
    const int pl4 = lane >> 2;
    const int dq  = lane & 3;
    ushort16* qn = qkv + (size_t)n * COUT * HW;
    #pragma unroll
    for (int s = 0; s < 2; ++s) {
        const int D = d0 + wm * 64 + s * 32;
        const int slot = D >> 5;
        ushort16* sb = qn + (size_t)slot * (HW * 32);
        #pragma unroll
        for (int g = 0; g < 4; ++g) {
            const int prow = g * 16 + pl4;
            const int c = s * 4 + dq;
            const uint4 val = *(const uint4*)&E[prow * 16 + ((c ^ (prow & 7)) * 2)];
            *(uint4*)(sb + (size_t)(p0 + wn * 64 + prow) * 32 + dq * 8) = val;
        }
    }
}

// ---------------------------------------------------------------------------
// Kernel 2 (v6): 5x5 neighborhood attention — NO LDS, cache-direct.
// Tile 2x32 pixels, 4 threads/pixel (8 dims each): 2048 blocks x 4 waves ->
// 8 blocks/CU, 32 waves/CU (2x TLP vs v5), zero barriers.
// Working set/tile (K+V halo 6x36 px x 128 B = 27 KB) is L1-resident;
// every neighbor load is a coalesced wave load ([p][d32] layout: 16 px x
// 64 B contiguous). QK: 4 fdot2 + 2-hop DPP quad butterfly. PV: 4 pk_fma.
// ---------------------------------------------------------------------------
__global__ __launch_bounds__(256) void attn_kernel(
    const ushort16* __restrict__ qkv, float* __restrict__ out)
{
    const int n    = blockIdx.z;
    const int head = blockIdx.y;
    const int h0 = (blockIdx.x >> 1) * 2;
    const int w0 = (blockIdx.x & 1) * 32;

    const int tid  = threadIdx.x;
    const int quar = tid & 3;          // d-quarter: dims 8q..8q+7
    const int pid  = tid >> 2;         // 0..63
    const int tr = pid >> 5, wc = pid & 31;
    const int h = h0 + tr, w = w0 + wc;
    const int p = h * WW + w;

    const uint4* Qb = (const uint4*)(qkv + ((size_t)(n * 24 + head)) * HW * 32);
    const uint4* Kb = (const uint4*)(qkv + ((size_t)(n * 24 + 8 + head)) * HW * 32);
    const uint4* Vb = (const uint4*)(qkv + ((size_t)(n * 24 + 16 + head)) * HW * 32);

    // Q: this thread's 8 dims, packed as 4x half2
    hf2 q[4];
    {
        union { uint4 u; hf2 h[4]; } c;
        c.u = Qb[(size_t)p * 4 + quar];
        #pragma unroll
        for (int i = 0; i < 4; ++i) q[i] = c.h[i];
    }

    // ---- scores: 8-dim partial dot, quad butterfly combine ----
    float sc[25];
    #pragma unroll
    for (int ky = 0; ky < 5; ++ky) {
        const int hh = h + ky - 2;
        #pragma unroll
        for (int kx = 0; kx < 5; ++kx) {
            const int ww = w + kx - 2;
            const bool valid = (hh >= 0 && hh < HH && ww >= 0 && ww < WW);
            float t = 0.f;
            if (valid) {
                const int pp = hh * WW + ww;
                union { uint4 u; hf2 h[4]; } a;
                a.u = Kb[(size_t)pp * 4 + quar];
                t = dot2acc(q[0], a.h[0], t);
                t = dot2acc(q[1], a.h[1], t);
                t = dot2acc(q[2], a.h[2], t);
                t = dot2acc(q[3], a.h[3], t);
            }
            t += dpp_xor1(t);
            t += dpp_xor2(t);
            sc[ky * 5 + kx] = valid ? t : -1e30f;
        }
    }

    float m = sc[0];
    #pragma unroll
    for (int k = 1; k < 25; ++k) m = fmaxf(m, sc[k]);
    float sum = 0.f;
    #pragma unroll
    for (int k = 0; k < 25; ++k) {
        float e = __expf(sc[k] - m);
        sc[k] = e;
        sum += e;
    }
    const float inv = 1.f / sum;

    // ---- PV: packed half2 accumulate over this thread's 8 dims ----
    hf2 acch[4];
    #pragma unroll
    for (int i = 0; i < 4; ++i) acch[i] = (hf2){(_Float16)0.f, (_Float16)0.f};
    #pragma unroll
    for (int ky = 0; ky < 5; ++ky) {
        const int hh = h + ky - 2;
        if (hh < 0 || hh >= HH) continue;
        #pragma unroll
        for (int kx = 0; kx < 5; ++kx) {
            const int ww = w + kx - 2;
            if (ww < 0 || ww >= WW) continue;
            const _Float16 af = (_Float16)sc[ky * 5 + kx];
            const hf2 ah = (hf2){af, af};
            const int pp = hh * WW + ww;
            union { uint4 u; hf2 h[4]; } v;
            v.u = Vb[(size_t)pp * 4 + quar];
            acch[0] += ah * v.h[0];
            acch[1] += ah * v.h[1];
            acch[2] += ah * v.h[2];
            acch[3] += ah * v.h[3];
        }
    }

    // ---- store: dims quar*8 .. quar*8+7 ----
    float* Ob = out + ((size_t)(n * 8 + head) * 32 + quar * 8) * HW + p;
    #pragma unroll
    for (int i = 0; i < 4; ++i) {
        Ob[(size_t)(2*i)   * HW] = (float)acch[i][0] * inv;
        Ob[(size_t)(2*i+1) * HW] = (float)acch[i][1] * inv;
    }
}

// ---------------------------------------------------------------------------
extern "C" void kernel_launch(void* const* d_in, const int* in_sizes, int n_in,
                              void* d_out, int out_size, void* d_ws, size_t ws_size,
                              hipStream_t stream) {
    const float* x  = (const float*)d_in[0];   // (4, 256, 64, 64)
    const float* wq = (const float*)d_in[1];   // (768, 256)
    const float* bq = (const float*)d_in[2];   // (768,)
    float* out = (float*)d_out;                // (4, 256, 64, 64) fp32
    ushort16* qkv = (ushort16*)d_ws;           // fp16 [4][24][4096][32] = 25 MB

    dim3 g1(HW / 128, COUT / 128, 4);          // (32, 6, 4) = 768 blocks
    qkv_gemm_kernel<<<g1, 256, 0, stream>>>(x, wq, bq, qkv);

    dim3 g2(64, 8, 4);                         // (32 h-tiles x 2 w-tiles, 8, 4) = 2048 blocks
    attn_kernel<<<g2, 256, 0, stream>>>(qkv, out);
}

// Round 13
// 42.524 us; speedup vs baseline: 1.4016x; 1.4016x over previous
//
#include <hip/hip_runtime.h>
#include <hip/hip_bf16.h>
#include <math.h>

#define CIN 256
#define COUT 768   // 3 * OUTC
#define OUTC 256
#define HH 64
#define WW 64
#define HW 4096

typedef unsigned int uint32;
typedef unsigned short ushort16;
typedef unsigned long long u64;

using short8 = __attribute__((ext_vector_type(8))) short;
using f32x4  = __attribute__((ext_vector_type(4))) float;
using hf2    = __attribute__((ext_vector_type(2))) _Float16;

__device__ inline uint32 pkbf2(float a, float b) {
    __hip_bfloat162 h = __float22bfloat162_rn(make_float2(a, b));
    union { __hip_bfloat162 h2; uint32 u; } cv; cv.h2 = h;
    return cv.u;
}
__device__ inline uint32 pkhf2(float a, float b) {
    union { _Float16 h[2]; uint32 u; } cv;
    cv.h[0] = (_Float16)a; cv.h[1] = (_Float16)b;
    return cv.u;
}
__device__ inline float dpp_xor1(float x) {
#if __has_builtin(__builtin_amdgcn_update_dpp)
    int i = __builtin_amdgcn_update_dpp(0, __float_as_int(x),
                                        0xB1, 0xF, 0xF, true);
    return __int_as_float(i);
#else
    return __shfl_xor(x, 1, 64);
#endif
}
// f32 += dot(h2, h2) — v_dot2_f32_f16 if available, else unpack-fma
__device__ inline float dot2acc(hf2 a, hf2 b, float c) {
#if __has_builtin(__builtin_amdgcn_fdot2)
    return __builtin_amdgcn_fdot2(a, b, c, false);
#else
    c = fmaf((float)a[0], (float)b[0], c);
    return fmaf((float)a[1], (float)b[1], c);
#endif
}

// ---------------------------------------------------------------------------
// Kernel 1 (v6): QKV projection = R10/R11 body + XCD-locality block remap.
// The 6 d-tiles sharing (n,p0) read the same 128-KB x slice; round-robin
// dispatch scatters them over 8 XCDs (all L3 hits, ~900cy). Remap so each
// XCD owns 16 (n,p0) superblocks x 6 d-tiles: x working set 2 MB < 4 MB L2,
// 5/6 of x reads become L2 hits (~200cy). Bijective: 768 = 8 xcd x 96.
// Output: qkv_f16[n][slot=d>>5][p][dlow=d&31]
// ---------------------------------------------------------------------------
#define LDSTR 40   // shorts per LDS row (32 + 8 pad)

__global__ __launch_bounds__(256) void qkv_gemm_kernel(
    const float* __restrict__ x, const float* __restrict__ wq,
    const float* __restrict__ bq, ushort16* __restrict__ qkv)
{
    __shared__ __align__(16) char smem[32768];
    ushort16* As = (ushort16*)smem;            // [128][LDSTR]
    ushort16* Bs = (ushort16*)smem + 128 * LDSTR;

    // ---- XCD-aware decode: raw -> (n, d0, p0) ----
    const int raw = blockIdx.x;        // 0..767
    const int xcd = raw & 7;           // hardware round-robin target
    const int idx = raw >> 3;          // 0..95 within XCD
    const int sb  = xcd * 16 + idx / 6;   // superblock (n,p0) 0..127
    const int d0t = idx - (idx / 6) * 6;  // 0..5
    const int n   = sb >> 5;
    const int d0  = d0t * 128;
    const int p0  = (sb & 31) * 128;

    const int tid = threadIdx.x;
    const int lane = tid & 63;
    const int wid  = tid >> 6;
    const int wm = wid >> 1;
    const int wn = wid & 1;

    const float* xb = x + (size_t)n * CIN * HW;

    const int arow = tid >> 2;
    const int akk  = (tid & 3) * 8;
    const float* aptr = wq + (size_t)(d0 + arow) * CIN + akk;
    const int bkg = (tid >> 6) * 8;
    const int bpg = (tid & 63) * 2;
    const float* bptr = xb + (size_t)bkg * HW + p0 + bpg;

    ushort16* awr0 = &As[arow * LDSTR + akk];
    ushort16* awr1 = &As[(arow + 64) * LDSTR + akk];
    ushort16* bwr0 = &Bs[bpg * LDSTR + bkg];
    ushort16* bwr1 = &Bs[(bpg + 1) * LDSTR + bkg];

    f32x4 acc[4][4];
    #pragma unroll
    for (int i = 0; i < 4; ++i)
        #pragma unroll
        for (int j = 0; j < 4; ++j) acc[i][j] = (f32x4){0.f, 0.f, 0.f, 0.f};

    float4 a_st[4];
    float2 b_st[8];

    {
        a_st[0] = *(const float4*)(aptr);
        a_st[1] = *(const float4*)(aptr + 4);
        a_st[2] = *(const float4*)(aptr + (size_t)64 * CIN);
        a_st[3] = *(const float4*)(aptr + (size_t)64 * CIN + 4);
        #pragma unroll
        for (int j = 0; j < 8; ++j)
            b_st[j] = *(const float2*)(bptr + (size_t)j * HW);
    }

    const int lrow = lane & 15;
    const int lk   = (lane >> 4) * 8;

    #pragma unroll 1
    for (int kt = 0; kt < 8; ++kt) {
        __syncthreads();

        {
            uint32 w0 = pkbf2(a_st[0].x, a_st[0].y), w1 = pkbf2(a_st[0].z, a_st[0].w);
            uint32 w2 = pkbf2(a_st[1].x, a_st[1].y), w3 = pkbf2(a_st[1].z, a_st[1].w);
            *(uint4*)awr0 = make_uint4(w0, w1, w2, w3);
            w0 = pkbf2(a_st[2].x, a_st[2].y); w1 = pkbf2(a_st[2].z, a_st[2].w);
            w2 = pkbf2(a_st[3].x, a_st[3].y); w3 = pkbf2(a_st[3].z, a_st[3].w);
            *(uint4*)awr1 = make_uint4(w0, w1, w2, w3);
            uint4 c0, c1;
            c0.x = pkbf2(b_st[0].x, b_st[1].x); c0.y = pkbf2(b_st[2].x, b_st[3].x);
            c0.z = pkbf2(b_st[4].x, b_st[5].x); c0.w = pkbf2(b_st[6].x, b_st[7].x);
            c1.x = pkbf2(b_st[0].y, b_st[1].y); c1.y = pkbf2(b_st[2].y, b_st[3].y);
            c1.z = pkbf2(b_st[4].y, b_st[5].y); c1.w = pkbf2(b_st[6].y, b_st[7].y);
            *(uint4*)bwr0 = c0;
            *(uint4*)bwr1 = c1;
        }

        if (kt < 7) {
            const int ko = (kt + 1) * 32;
            a_st[0] = *(const float4*)(aptr + ko);
            a_st[1] = *(const float4*)(aptr + ko + 4);
            a_st[2] = *(const float4*)(aptr + (size_t)64 * CIN + ko);
            a_st[3] = *(const float4*)(aptr + (size_t)64 * CIN + ko + 4);
            #pragma unroll
            for (int j = 0; j < 8; ++j)
                b_st[j] = *(const float2*)(bptr + (size_t)(ko + j) * HW);
        }

        __syncthreads();

        short8 af[4], bf[4];
        #pragma unroll
        for (int fm = 0; fm < 4; ++fm)
            af[fm] = *(const short8*)&As[(wm * 64 + fm * 16 + lrow) * LDSTR + lk];
        #pragma unroll
        for (int fn = 0; fn < 4; ++fn)
            bf[fn] = *(const short8*)&Bs[(wn * 64 + fn * 16 + lrow) * LDSTR + lk];
        #pragma unroll
        for (int fm = 0; fm < 4; ++fm)
            #pragma unroll
            for (int fn = 0; fn < 4; ++fn)
                acc[fm][fn] = __builtin_amdgcn_mfma_f32_16x16x32_bf16(
                    af[fm], bf[fn], acc[fm][fn], 0, 0, 0);
    }

    // ---- epilogue: LDS transpose -> coalesced stores ----
    __syncthreads();

    u64* E = (u64*)smem + (size_t)wid * 1024;

    const int hi4 = lane >> 4;
    #pragma unroll
    for (int fm = 0; fm < 4; ++fm) {
        const int D = d0 + wm * 64 + fm * 16 + hi4 * 4;
        const float4 bias = *(const float4*)(&bq[D]);
        const int cell = fm * 2 + (hi4 >> 1);
        const int half = hi4 & 1;
        #pragma unroll
        for (int fn = 0; fn < 4; ++fn) {
            const int pl = fn * 16 + lrow;
            f32x4 v = acc[fm][fn];
            u64 pk = (u64)pkhf2(v[0] + bias.x, v[1] + bias.y)
                   | ((u64)pkhf2(v[2] + bias.z, v[3] + bias.w) << 32);
            E[pl * 16 + (cell ^ (pl & 7)) * 2 + half] = pk;
        }
    }
    const int pl4 = lane >> 2;
    const int dq  = lane & 3;
    ushort16* qn = qkv + (size_t)n * COUT * HW;
    #pragma unroll
    for (int s = 0; s < 2; ++s) {
        const int D = d0 + wm * 64 + s * 32;
        const int slot = D >> 5;
        ushort16* sb2 = qn + (size_t)slot * (HW * 32);
        #pragma unroll
        for (int g = 0; g < 4; ++g) {
            const int prow = g * 16 + pl4;
            const int c = s * 4 + dq;
            const uint4 val = *(const uint4*)&E[prow * 16 + ((c ^ (prow & 7)) * 2)];
            *(uint4*)(sb2 + (size_t)(p0 + wn * 64 + prow) * 32 + dq * 8) = val;
        }
    }
}

// ---------------------------------------------------------------------------
// Kernel 2: 5x5 neighborhood attention (EXACT R11 v5 body, ~19.8 us).
// LDS-staged K/V, packed math (fdot2 QK, pk_fma PV), DPP combine.
// ---------------------------------------------------------------------------
#define TR 4
#define TC 32
#define HR 8
#define HC 36
#define NPIX (HR*HC)  // 288

__global__ __launch_bounds__(256) void attn_kernel(
    const ushort16* __restrict__ qkv, float* __restrict__ out)
{
    __shared__ uint4 Ks[NPIX * 4];   // 18 KB
    __shared__ uint4 Vs[NPIX * 4];   // 18 KB

    const int n    = blockIdx.z;
    const int head = blockIdx.y;
    const int ht = blockIdx.x >> 1;
    const int wt = blockIdx.x & 1;
    const int h0 = ht * TR;
    const int w0 = wt * TC;

    const int tid  = threadIdx.x;
    const int half = tid & 1;
    const int wc   = (tid >> 1) & 31;
    const int tr   = tid >> 6;

    const int h = h0 + tr, w = w0 + wc;
    const int p = h * WW + w;

    const uint4* Kb = (const uint4*)(qkv + ((size_t)(n * 24 + 8 + head)) * HW * 32);
    const uint4* Vb = (const uint4*)(qkv + ((size_t)(n * 24 + 16 + head)) * HW * 32);

    for (int c = tid; c < 2 * NPIX * 4; c += 256) {
        const int b  = (c >= NPIX * 4);
        const int cc = c - b * NPIX * 4;
        const int pix = cc >> 2, i = cc & 3;
        const int hr = pix / HC, cw = pix - hr * HC;
        const int hh = h0 + hr - 2, ww = w0 + cw - 2;
        if (hh >= 0 && hh < HH && ww >= 0 && ww < WW) {
            const int pp = hh * WW + ww;
            const uint4 v = (b ? Vb : Kb)[(size_t)pp * 4 + i];
            const int unit = (pix * 4 + i) ^ (pix & 7);
            (b ? Vs : Ks)[unit] = v;
        }
    }

    hf2 q[8];
    {
        const uint4* Qp = (const uint4*)(qkv + (((size_t)(n * 24 + head)) * HW + p) * 32);
        union { uint4 u; hf2 h[4]; } c0, c1;
        c0.u = Qp[half * 2];
        c1.u = Qp[half * 2 + 1];
        #pragma unroll
        for (int i = 0; i < 4; ++i) { q[i] = c0.h[i]; q[4 + i] = c1.h[i]; }
    }

    __syncthreads();

    float sc[25];
    #pragma unroll
    for (int ky = 0; ky < 5; ++ky) {
        const int hh = h + ky - 2;
        const int hr = tr + ky;
        #pragma unroll
        for (int kx = 0; kx < 5; ++kx) {
            const int ww = w + kx - 2;
            float s;
            if (hh >= 0 && hh < HH && ww >= 0 && ww < WW) {
                const int pix = hr * HC + (wc + kx);
                const int u0 = (pix * 4 + half * 2)     ^ (pix & 7);
                const int u1 = (pix * 4 + half * 2 + 1) ^ (pix & 7);
                union { uint4 u; hf2 h[4]; } a, b;
                a.u = Ks[u0]; b.u = Ks[u1];
                float t = 0.f;
                t = dot2acc(q[0], a.h[0], t);
                t = dot2acc(q[1], a.h[1], t);
                t = dot2acc(q[2], a.h[2], t);
                t = dot2acc(q[3], a.h[3], t);
                t = dot2acc(q[4], b.h[0], t);
                t = dot2acc(q[5], b.h[1], t);
                t = dot2acc(q[6], b.h[2], t);
                t = dot2acc(q[7], b.h[3], t);
                s = t;
            } else {
                s = -1e30f;
            }
            sc[ky * 5 + kx] = s;
        }
    }
    #pragma unroll
    for (int k = 0; k < 25; ++k) {
        float o = dpp_xor1(sc[k]);
        sc[k] = (sc[k] <= -1e29f) ? sc[k] : sc[k] + o;
    }

    float m = sc[0];
    #pragma unroll
    for (int k = 1; k < 25; ++k) m = fmaxf(m, sc[k]);
    float sum = 0.f;
    #pragma unroll
    for (int k = 0; k < 25; ++k) {
        float e = __expf(sc[k] - m);
        sc[k] = e;
        sum += e;
    }
    const float inv = 1.f / sum;

    hf2 acch[8];
    #pragma unroll
    for (int i = 0; i < 8; ++i) acch[i] = (hf2){(_Float16)0.f, (_Float16)0.f};
    #pragma unroll
    for (int ky = 0; ky < 5; ++ky) {
        const int hh = h + ky - 2;
        if (hh < 0 || hh >= HH) continue;
        const int hr = tr + ky;
        #pragma unroll
        for (int kx = 0; kx < 5; ++kx) {
            const int ww = w + kx - 2;
            if (ww < 0 || ww >= WW) continue;
            const _Float16 af = (_Float16)sc[ky * 5 + kx];
            const hf2 ah = (hf2){af, af};
            const int pix = hr * HC + (wc + kx);
            const int u0 = (pix * 4 + half * 2)     ^ (pix & 7);
            const int u1 = (pix * 4 + half * 2 + 1) ^ (pix & 7);
            union { uint4 u; hf2 h[4]; } xv, yv;
            xv.u = Vs[u0]; yv.u = Vs[u1];
            acch[0] += ah * xv.h[0];
            acch[1] += ah * xv.h[1];
            acch[2] += ah * xv.h[2];
            acch[3] += ah * xv.h[3];
            acch[4] += ah * yv.h[0];
            acch[5] += ah * yv.h[1];
            acch[6] += ah * yv.h[2];
            acch[7] += ah * yv.h[3];
        }
    }

    float* Ob = out + ((size_t)(n * 8 + head) * 32 + half * 16) * HW + p;
    #pragma unroll
    for (int i = 0; i < 8; ++i) {
        Ob[(size_t)(2*i)   * HW] = (float)acch[i][0] * inv;
        Ob[(size_t)(2*i+1) * HW] = (float)acch[i][1] * inv;
    }
}

// ---------------------------------------------------------------------------
extern "C" void kernel_launch(void* const* d_in, const int* in_sizes, int n_in,
                              void* d_out, int out_size, void* d_ws, size_t ws_size,
                              hipStream_t stream) {
    const float* x  = (const float*)d_in[0];   // (4, 256, 64, 64)
    const float* wq = (const float*)d_in[1];   // (768, 256)
    const float* bq = (const float*)d_in[2];   // (768,)
    float* out = (float*)d_out;                // (4, 256, 64, 64) fp32
    ushort16* qkv = (ushort16*)d_ws;           // fp16 [4][24][4096][32] = 25 MB

    qkv_gemm_kernel<<<768, 256, 0, stream>>>(x, wq, bq, qkv);

    dim3 g2(32, 8, 4);
    attn_kernel<<<g2, 256, 0, stream>>>(qkv, out);
}

// Round 14
// 41.475 us; speedup vs baseline: 1.4371x; 1.0253x over previous
//
#include <hip/hip_runtime.h>
#include <hip/hip_bf16.h>
#include <math.h>

#define CIN 256
#define COUT 768   // 3 * OUTC
#define OUTC 256
#define HH 64
#define WW 64
#define HW 4096

typedef unsigned int uint32;
typedef unsigned short ushort16;
typedef unsigned long long u64;

using short8 = __attribute__((ext_vector_type(8))) short;
using f32x4  = __attribute__((ext_vector_type(4))) float;
using hf2    = __attribute__((ext_vector_type(2))) _Float16;

__device__ inline uint32 pkbf2(float a, float b) {
    __hip_bfloat162 h = __float22bfloat162_rn(make_float2(a, b));
    union { __hip_bfloat162 h2; uint32 u; } cv; cv.h2 = h;
    return cv.u;
}
__device__ inline uint32 pkhf2(float a, float b) {
    union { _Float16 h[2]; uint32 u; } cv;
    cv.h[0] = (_Float16)a; cv.h[1] = (_Float16)b;
    return cv.u;
}
__device__ inline float dpp_xor1(float x) {
#if __has_builtin(__builtin_amdgcn_update_dpp)
    int i = __builtin_amdgcn_update_dpp(0, __float_as_int(x),
                                        0xB1, 0xF, 0xF, true);
    return __int_as_float(i);
#else
    return __shfl_xor(x, 1, 64);
#endif
}
// f32 += dot(h2, h2) — v_dot2_f32_f16 if available, else unpack-fma
__device__ inline float dot2acc(hf2 a, hf2 b, float c) {
#if __has_builtin(__builtin_amdgcn_fdot2)
    return __builtin_amdgcn_fdot2(a, b, c, false);
#else
    c = fmaf((float)a[0], (float)b[0], c);
    return fmaf((float)a[1], (float)b[1], c);
#endif
}

// ---------------------------------------------------------------------------
// Kernel 1 (v7): QKV projection = R11 body + DEPTH-2 register prefetch.
// Loads for K-tile kt are issued TWO iterations before their cvt+LDS write
// (ping-pong sets, unroll-2 -> static reg indexing). Window ~2 phases
// (>1200cy) now covers the ~900cy L3 miss latency on x.
// Output: qkv_f16[n][slot=d>>5][p][dlow=d&31]
// ---------------------------------------------------------------------------
#define LDSTR 40   // shorts per LDS row (32 + 8 pad)

__global__ __launch_bounds__(256) void qkv_gemm_kernel(
    const float* __restrict__ x, const float* __restrict__ wq,
    const float* __restrict__ bq, ushort16* __restrict__ qkv)
{
    __shared__ __align__(16) char smem[32768];
    ushort16* As = (ushort16*)smem;            // [128][LDSTR]
    ushort16* Bs = (ushort16*)smem + 128 * LDSTR;

    const int n   = blockIdx.z;
    const int d0  = blockIdx.y * 128;
    const int p0  = blockIdx.x * 128;
    const int tid = threadIdx.x;
    const int lane = tid & 63;
    const int wid  = tid >> 6;
    const int wm = wid >> 1;
    const int wn = wid & 1;

    const float* xb = x + (size_t)n * CIN * HW;

    const int arow = tid >> 2;
    const int akk  = (tid & 3) * 8;
    const float* aptr = wq + (size_t)(d0 + arow) * CIN + akk;
    const int bkg = (tid >> 6) * 8;
    const int bpg = (tid & 63) * 2;
    const float* bptr = xb + (size_t)bkg * HW + p0 + bpg;

    ushort16* awr0 = &As[arow * LDSTR + akk];
    ushort16* awr1 = &As[(arow + 64) * LDSTR + akk];
    ushort16* bwr0 = &Bs[bpg * LDSTR + bkg];
    ushort16* bwr1 = &Bs[(bpg + 1) * LDSTR + bkg];

    f32x4 acc[4][4];
    #pragma unroll
    for (int i = 0; i < 4; ++i)
        #pragma unroll
        for (int j = 0; j < 4; ++j) acc[i][j] = (f32x4){0.f, 0.f, 0.f, 0.f};

    const int lrow = lane & 15;
    const int lk   = (lane >> 4) * 8;

    // two ping-pong staging sets (static names -> registers)
    float4 a0[4], a1[4];
    float2 b0[8], b1[8];

#define LOAD_SET(aS, bS, ko) do {                                         \
        aS[0] = *(const float4*)(aptr + (ko));                            \
        aS[1] = *(const float4*)(aptr + (ko) + 4);                        \
        aS[2] = *(const float4*)(aptr + (size_t)64 * CIN + (ko));         \
        aS[3] = *(const float4*)(aptr + (size_t)64 * CIN + (ko) + 4);     \
        _Pragma("unroll")                                                 \
        for (int j = 0; j < 8; ++j)                                       \
            bS[j] = *(const float2*)(bptr + (size_t)((ko) + j) * HW);     \
    } while (0)

#define WRITE_SET(aS, bS) do {                                            \
        uint32 w0 = pkbf2(aS[0].x, aS[0].y), w1 = pkbf2(aS[0].z, aS[0].w);\
        uint32 w2 = pkbf2(aS[1].x, aS[1].y), w3 = pkbf2(aS[1].z, aS[1].w);\
        *(uint4*)awr0 = make_uint4(w0, w1, w2, w3);                       \
        w0 = pkbf2(aS[2].x, aS[2].y); w1 = pkbf2(aS[2].z, aS[2].w);       \
        w2 = pkbf2(aS[3].x, aS[3].y); w3 = pkbf2(aS[3].z, aS[3].w);       \
        *(uint4*)awr1 = make_uint4(w0, w1, w2, w3);                       \
        uint4 c0, c1;                                                     \
        c0.x = pkbf2(bS[0].x, bS[1].x); c0.y = pkbf2(bS[2].x, bS[3].x);   \
        c0.z = pkbf2(bS[4].x, bS[5].x); c0.w = pkbf2(bS[6].x, bS[7].x);   \
        c1.x = pkbf2(bS[0].y, bS[1].y); c1.y = pkbf2(bS[2].y, bS[3].y);   \
        c1.z = pkbf2(bS[4].y, bS[5].y); c1.w = pkbf2(bS[6].y, bS[7].y);   \
        *(uint4*)bwr0 = c0;                                               \
        *(uint4*)bwr1 = c1;                                               \
    } while (0)

#define COMPUTE() do {                                                    \
        short8 af[4], bf[4];                                              \
        _Pragma("unroll")                                                 \
        for (int fm = 0; fm < 4; ++fm)                                    \
            af[fm] = *(const short8*)&As[(wm * 64 + fm * 16 + lrow) * LDSTR + lk]; \
        _Pragma("unroll")                                                 \
        for (int fn = 0; fn < 4; ++fn)                                    \
            bf[fn] = *(const short8*)&Bs[(wn * 64 + fn * 16 + lrow) * LDSTR + lk]; \
        _Pragma("unroll")                                                 \
        for (int fm = 0; fm < 4; ++fm)                                    \
            _Pragma("unroll")                                             \
            for (int fn = 0; fn < 4; ++fn)                                \
                acc[fm][fn] = __builtin_amdgcn_mfma_f32_16x16x32_bf16(    \
                    af[fm], bf[fn], acc[fm][fn], 0, 0, 0);                \
    } while (0)

    // prologue: kt0 -> set0, kt1 -> set1
    LOAD_SET(a0, b0, 0);
    LOAD_SET(a1, b1, 32);

    #pragma unroll 1
    for (int kt = 0; kt < 8; kt += 2) {
        // ---- even kt: uses set0, refills set0 with kt+2 ----
        __syncthreads();                  // prev MFMA phase done reading LDS
        WRITE_SET(a0, b0);                // waits (counted vmcnt) on kt's loads
        if (kt + 2 < 8) LOAD_SET(a0, b0, (kt + 2) * 32);
        __syncthreads();                  // LDS tile visible
        COMPUTE();

        // ---- odd kt+1: uses set1, refills set1 with kt+3 ----
        __syncthreads();
        WRITE_SET(a1, b1);
        if (kt + 3 < 8) LOAD_SET(a1, b1, (kt + 3) * 32);
        __syncthreads();
        COMPUTE();
    }
#undef LOAD_SET
#undef WRITE_SET
#undef COMPUTE

    // ---- epilogue: LDS transpose -> coalesced stores (R10/R11) ----
    __syncthreads();

    u64* E = (u64*)smem + (size_t)wid * 1024;

    const int hi4 = lane >> 4;
    #pragma unroll
    for (int fm = 0; fm < 4; ++fm) {
        const int D = d0 + wm * 64 + fm * 16 + hi4 * 4;
        const float4 bias = *(const float4*)(&bq[D]);
        const int cell = fm * 2 + (hi4 >> 1);
        const int half = hi4 & 1;
        #pragma unroll
        for (int fn = 0; fn < 4; ++fn) {
            const int pl = fn * 16 + lrow;
            f32x4 v = acc[fm][fn];
            u64 pk = (u64)pkhf2(v[0] + bias.x, v[1] + bias.y)
                   | ((u64)pkhf2(v[2] + bias.z, v[3] + bias.w) << 32);
            E[pl * 16 + (cell ^ (pl & 7)) * 2 + half] = pk;
        }
    }
    const int pl4 = lane >> 2;
    const int dq  = lane & 3;
    ushort16* qn = qkv + (size_t)n * COUT * HW;
    #pragma unroll
    for (int s = 0; s < 2; ++s) {
        const int D = d0 + wm * 64 + s * 32;
        const int slot = D >> 5;
        ushort16* sb2 = qn + (size_t)slot * (HW * 32);
        #pragma unroll
        for (int g = 0; g < 4; ++g) {
            const int prow = g * 16 + pl4;
            const int c = s * 4 + dq;
            const uint4 val = *(const uint4*)&E[prow * 16 + ((c ^ (prow & 7)) * 2)];
            *(uint4*)(sb2 + (size_t)(p0 + wn * 64 + prow) * 32 + dq * 8) = val;
        }
    }
}

// ---------------------------------------------------------------------------
// Kernel 2: 5x5 neighborhood attention (EXACT R11 v5 body, ~19.6 us).
// ---------------------------------------------------------------------------
#define TR 4
#define TC 32
#define HR 8
#define HC 36
#define NPIX (HR*HC)  // 288

__global__ __launch_bounds__(256) void attn_kernel(
    const ushort16* __restrict__ qkv, float* __restrict__ out)
{
    __shared__ uint4 Ks[NPIX * 4];   // 18 KB
    __shared__ uint4 Vs[NPIX * 4];   // 18 KB

    const int n    = blockIdx.z;
    const int head = blockIdx.y;
    const int ht = blockIdx.x >> 1;
    const int wt = blockIdx.x & 1;
    const int h0 = ht * TR;
    const int w0 = wt * TC;

    const int tid  = threadIdx.x;
    const int half = tid & 1;
    const int wc   = (tid >> 1) & 31;
    const int tr   = tid >> 6;

    const int h = h0 + tr, w = w0 + wc;
    const int p = h * WW + w;

    const uint4* Kb = (const uint4*)(qkv + ((size_t)(n * 24 + 8 + head)) * HW * 32);
    const uint4* Vb = (const uint4*)(qkv + ((size_t)(n * 24 + 16 + head)) * HW * 32);

    for (int c = tid; c < 2 * NPIX * 4; c += 256) {
        const int b  = (c >= NPIX * 4);
        const int cc = c - b * NPIX * 4;
        const int pix = cc >> 2, i = cc & 3;
        const int hr = pix / HC, cw = pix - hr * HC;
        const int hh = h0 + hr - 2, ww = w0 + cw - 2;
        if (hh >= 0 && hh < HH && ww >= 0 && ww < WW) {
            const int pp = hh * WW + ww;
            const uint4 v = (b ? Vb : Kb)[(size_t)pp * 4 + i];
            const int unit = (pix * 4 + i) ^ (pix & 7);
            (b ? Vs : Ks)[unit] = v;
        }
    }

    hf2 q[8];
    {
        const uint4* Qp = (const uint4*)(qkv + (((size_t)(n * 24 + head)) * HW + p) * 32);
        union { uint4 u; hf2 h[4]; } c0, c1;
        c0.u = Qp[half * 2];
        c1.u = Qp[half * 2 + 1];
        #pragma unroll
        for (int i = 0; i < 4; ++i) { q[i] = c0.h[i]; q[4 + i] = c1.h[i]; }
    }

    __syncthreads();

    float sc[25];
    #pragma unroll
    for (int ky = 0; ky < 5; ++ky) {
        const int hh = h + ky - 2;
        const int hr = tr + ky;
        #pragma unroll
        for (int kx = 0; kx < 5; ++kx) {
            const int ww = w + kx - 2;
            float s;
            if (hh >= 0 && hh < HH && ww >= 0 && ww < WW) {
                const int pix = hr * HC + (wc + kx);
                const int u0 = (pix * 4 + half * 2)     ^ (pix & 7);
                const int u1 = (pix * 4 + half * 2 + 1) ^ (pix & 7);
                union { uint4 u; hf2 h[4]; } a, b;
                a.u = Ks[u0]; b.u = Ks[u1];
                float t = 0.f;
                t = dot2acc(q[0], a.h[0], t);
                t = dot2acc(q[1], a.h[1], t);
                t = dot2acc(q[2], a.h[2], t);
                t = dot2acc(q[3], a.h[3], t);
                t = dot2acc(q[4], b.h[0], t);
                t = dot2acc(q[5], b.h[1], t);
                t = dot2acc(q[6], b.h[2], t);
                t = dot2acc(q[7], b.h[3], t);
                s = t;
            } else {
                s = -1e30f;
            }
            sc[ky * 5 + kx] = s;
        }
    }
    #pragma unroll
    for (int k = 0; k < 25; ++k) {
        float o = dpp_xor1(sc[k]);
        sc[k] = (sc[k] <= -1e29f) ? sc[k] : sc[k] + o;
    }

    float m = sc[0];
    #pragma unroll
    for (int k = 1; k < 25; ++k) m = fmaxf(m, sc[k]);
    float sum = 0.f;
    #pragma unroll
    for (int k = 0; k < 25; ++k) {
        float e = __expf(sc[k] - m);
        sc[k] = e;
        sum += e;
    }
    const float inv = 1.f / sum;

    hf2 acch[8];
    #pragma unroll
    for (int i = 0; i < 8; ++i) acch[i] = (hf2){(_Float16)0.f, (_Float16)0.f};
    #pragma unroll
    for (int ky = 0; ky < 5; ++ky) {
        const int hh = h + ky - 2;
        if (hh < 0 || hh >= HH) continue;
        const int hr = tr + ky;
        #pragma unroll
        for (int kx = 0; kx < 5; ++kx) {
            const int ww = w + kx - 2;
            if (ww < 0 || ww >= WW) continue;
            const _Float16 af = (_Float16)sc[ky * 5 + kx];
            const hf2 ah = (hf2){af, af};
            const int pix = hr * HC + (wc + kx);
            const int u0 = (pix * 4 + half * 2)     ^ (pix & 7);
            const int u1 = (pix * 4 + half * 2 + 1) ^ (pix & 7);
            union { uint4 u; hf2 h[4]; } xv, yv;
            xv.u = Vs[u0]; yv.u = Vs[u1];
            acch[0] += ah * xv.h[0];
            acch[1] += ah * xv.h[1];
            acch[2] += ah * xv.h[2];
            acch[3] += ah * xv.h[3];
            acch[4] += ah * yv.h[0];
            acch[5] += ah * yv.h[1];
            acch[6] += ah * yv.h[2];
            acch[7] += ah * yv.h[3];
        }
    }

    float* Ob = out + ((size_t)(n * 8 + head) * 32 + half * 16) * HW + p;
    #pragma unroll
    for (int i = 0; i < 8; ++i) {
        Ob[(size_t)(2*i)   * HW] = (float)acch[i][0] * inv;
        Ob[(size_t)(2*i+1) * HW] = (float)acch[i][1] * inv;
    }
}

// ---------------------------------------------------------------------------
extern "C" void kernel_launch(void* const* d_in, const int* in_sizes, int n_in,
                              void* d_out, int out_size, void* d_ws, size_t ws_size,
                              hipStream_t stream) {
    const float* x  = (const float*)d_in[0];   // (4, 256, 64, 64)
    const float* wq = (const float*)d_in[1];   // (768, 256)
    const float* bq = (const float*)d_in[2];   // (768,)
    float* out = (float*)d_out;                // (4, 256, 64, 64) fp32
    ushort16* qkv = (ushort16*)d_ws;           // fp16 [4][24][4096][32] = 25 MB

    dim3 g1(HW / 128, COUT / 128, 4);          // (32, 6, 4) = 768 blocks
    qkv_gemm_kernel<<<g1, 256, 0, stream>>>(x, wq, bq, qkv);

    dim3 g2(32, 8, 4);
    attn_kernel<<<g2, 256, 0, stream>>>(qkv, out);
}